// Round 1
// baseline (873.925 us; speedup 1.0000x reference)
//
#include <hip/hip_runtime.h>
#include <hip/hip_bf16.h>

typedef unsigned short u16;
typedef __bf16 bf16x8 __attribute__((ext_vector_type(8)));
typedef float f32x4 __attribute__((ext_vector_type(4)));

// ---------- helpers ----------

__device__ __forceinline__ u16 f32_to_bf16(float f) {
    unsigned int u = __float_as_uint(f);
    unsigned int r = (u + 0x7FFFu + ((u >> 16) & 1u)) >> 16;  // RNE
    return (u16)r;
}

__device__ __forceinline__ unsigned pack2(float a, float b) {
    return (unsigned)f32_to_bf16(a) | ((unsigned)f32_to_bf16(b) << 16);
}

__device__ __forceinline__ void load_lds16(const void* g, void* s) {
    __builtin_amdgcn_global_load_lds(
        (__attribute__((address_space(1))) void*)g,
        (__attribute__((address_space(3))) void*)s,
        16, 0, 0);
}

// ---------- kernel 1: x fp32 -> bf16 (8 elems/thread, 16B stores) ----------

__global__ __launch_bounds__(256) void convert_f32_bf16(
        const float* __restrict__ in, u16* __restrict__ out) {
    int i = blockIdx.x * 256 + threadIdx.x;            // grid exactly n/8
    const float4* in4 = (const float4*)in;
    float4 v0 = in4[(size_t)i * 2];
    float4 v1 = in4[(size_t)i * 2 + 1];
    uint4 r;
    r.x = pack2(v0.x, v0.y);
    r.y = pack2(v0.z, v0.w);
    r.z = pack2(v1.x, v1.y);
    r.w = pack2(v1.z, v1.w);
    ((uint4*)out)[i] = r;
}

// ---------- kernel 2: dequant indices -> y_bf (8 elems/thread) ----------

__global__ __launch_bounds__(256) void dequant_kernel(
        const int* __restrict__ idx, const float* __restrict__ cent,
        u16* __restrict__ out) {
    __shared__ float lut[16];
    if (threadIdx.x < 16) lut[threadIdx.x] = cent[threadIdx.x];
    __syncthreads();
    int i = blockIdx.x * 256 + threadIdx.x;
    const int4* in4 = (const int4*)idx;
    int4 a = in4[(size_t)i * 2];
    int4 b = in4[(size_t)i * 2 + 1];
    uint4 r;
    r.x = pack2(lut[a.x], lut[a.y]);
    r.y = pack2(lut[a.z], lut[a.w]);
    r.z = pack2(lut[b.x], lut[b.y]);
    r.w = pack2(lut[b.z], lut[b.w]);
    ((uint4*)out)[i] = r;
}

// ---------- kernel 3: Pi (4096x4096 fp32) -> Pi^T bf16 ----------
// tile 32x32 through padded LDS; reads and writes both coalesced.

__global__ __launch_bounds__(256) void transpose_to_bf16(
        const float* __restrict__ Pi, u16* __restrict__ PiT) {
    __shared__ float tile[32][33];
    const int tx = threadIdx.x;      // 0..31
    const int ty = threadIdx.y;      // 0..7
    const int j0 = blockIdx.x * 32;  // Pi column block
    const int k0 = blockIdx.y * 32;  // Pi row block
#pragma unroll
    for (int i = 0; i < 4; i++)
        tile[ty + 8 * i][tx] = Pi[(size_t)(k0 + ty + 8 * i) * 4096 + j0 + tx];
    __syncthreads();
#pragma unroll
    for (int i = 0; i < 4; i++)
        PiT[(size_t)(j0 + ty + 8 * i) * 4096 + k0 + tx] =
            f32_to_bf16(tile[tx][ty + 8 * i]);
}

// ---------- GEMM: C[m][n] = sum_k A[m][k] * B[n][k]  (B stored N x K) ----------
// m97 structure: 128x128 block tile, BK=32, 4 waves each computing 64x64 via
// 4x4 grid of 16x16x32 bf16 MFMAs. global_load_lds width-16 staging (LDS dest
// must be wave-uniform base + lane*16 -> unpadded row-major tiles).
// MODE 0: store bf16, scale by aux[row]   (W = (yhat@Pi) * row_norms)
// MODE 1: store fp32, add aux[col]        (out = x@W^T + bias)

template <int MODE>
__global__ __launch_bounds__(256) void gemm_bt(
        const u16* __restrict__ A, const u16* __restrict__ Bm,
        const float* __restrict__ aux, float* __restrict__ Cf,
        u16* __restrict__ Cb, int M, int N, int K) {
    __shared__ u16 As[128 * 32];
    __shared__ u16 Bs[128 * 32];

    const int tid  = threadIdx.x;
    const int lane = tid & 63;
    const int wv   = tid >> 6;
    const int wr   = (wv >> 1) << 6;   // wave row offset in block tile
    const int wc   = (wv & 1) << 6;    // wave col offset in block tile
    const int m0   = blockIdx.y * 128;
    const int n0   = blockIdx.x * 128;

    // staging: thread t covers bytes [t*16, t*16+16) of each 8KB tile
    const int rT = tid >> 2;           // row in tile 0..63 (and +64)
    const int cT = (tid & 3) << 3;     // element col in tile {0,8,16,24}
    const u16* Ag = A + (size_t)(m0 + rT) * K + cT;
    const u16* Bg = Bm + (size_t)(n0 + rT) * K + cT;
    u16* Asd = &As[rT * 32 + cT];
    u16* Bsd = &Bs[rT * 32 + cT];

    const int fr = lane & 15;          // row/col within 16-tile
    const int fk = (lane >> 4) << 3;   // k offset {0,8,16,24}

    f32x4 acc[4][4];
#pragma unroll
    for (int i = 0; i < 4; i++)
#pragma unroll
        for (int j = 0; j < 4; j++) acc[i][j] = (f32x4){0.f, 0.f, 0.f, 0.f};

    for (int k0 = 0; k0 < K; k0 += 32) {
        load_lds16(Ag + k0, Asd);
        load_lds16(Ag + (size_t)64 * K + k0, Asd + 64 * 32);
        load_lds16(Bg + k0, Bsd);
        load_lds16(Bg + (size_t)64 * K + k0, Bsd + 64 * 32);
        __syncthreads();   // compiler emits vmcnt(0) drain before barrier

        bf16x8 af[4], bfr[4];
#pragma unroll
        for (int mi = 0; mi < 4; mi++)
            af[mi] = *(const bf16x8*)&As[(wr + mi * 16 + fr) * 32 + fk];
#pragma unroll
        for (int ni = 0; ni < 4; ni++)
            bfr[ni] = *(const bf16x8*)&Bs[(wc + ni * 16 + fr) * 32 + fk];
#pragma unroll
        for (int mi = 0; mi < 4; mi++)
#pragma unroll
            for (int ni = 0; ni < 4; ni++)
                acc[mi][ni] = __builtin_amdgcn_mfma_f32_16x16x32_bf16(
                    af[mi], bfr[ni], acc[mi][ni], 0, 0, 0);
        __syncthreads();   // protect LDS from next iteration's staging
    }

    // epilogue — C/D layout: col = lane&15, row = (lane>>4)*4 + reg
    const int colb = n0 + wc + fr;
    const int rowb = m0 + wr + ((lane >> 4) << 2);
#pragma unroll
    for (int mi = 0; mi < 4; mi++) {
#pragma unroll
        for (int r = 0; r < 4; r++) {
            const int row = rowb + mi * 16 + r;
            if (MODE == 0) {
                const float s = aux[row];
#pragma unroll
                for (int ni = 0; ni < 4; ni++)
                    Cb[(size_t)row * N + colb + ni * 16] =
                        f32_to_bf16(acc[mi][ni][r] * s);
            } else {
#pragma unroll
                for (int ni = 0; ni < 4; ni++)
                    Cf[(size_t)row * N + colb + ni * 16] =
                        acc[mi][ni][r] + aux[colb + ni * 16];
            }
        }
    }
}

// ---------- launch ----------

extern "C" void kernel_launch(void* const* d_in, const int* in_sizes, int n_in,
                              void* d_out, int out_size, void* d_ws, size_t ws_size,
                              hipStream_t stream) {
    const float* x         = (const float*)d_in[0];   // (4,2048,4096) fp32
    const int*   indices   = (const int*)d_in[1];     // (4096,4096) int32
    const float* centroids = (const float*)d_in[2];   // (16,) fp32
    const float* Pi        = (const float*)d_in[3];   // (4096,4096) fp32
    const float* row_norms = (const float*)d_in[4];   // (4096,) fp32
    const float* bias      = (const float*)d_in[5];   // (4096,) fp32
    float* out = (float*)d_out;                       // (4,2048,4096) fp32

    // workspace layout (bf16 as u16): total 160 MiB
    u16* x_bf = (u16*)d_ws;                 // 8192*4096 = 33554432 elems
    u16* y_bf = x_bf + (size_t)33554432;    // 4096*4096
    u16* pi_t = y_bf + (size_t)16777216;    // 4096*4096 (Pi transposed)
    u16* w_bf = pi_t + (size_t)16777216;    // 4096*4096

    // 1) x -> bf16: 33554432/8 per-thread -> 16384 blocks
    convert_f32_bf16<<<16384, 256, 0, stream>>>(x, x_bf);
    // 2) dequant: 16777216/8 -> 8192 blocks
    dequant_kernel<<<8192, 256, 0, stream>>>(indices, centroids, y_bf);
    // 3) Pi -> Pi^T bf16
    transpose_to_bf16<<<dim3(128, 128), dim3(32, 8), 0, stream>>>(Pi, pi_t);
    // 4) W = (yhat @ Pi) * row_norms : A=y_bf (4096xK), B=pi_t (4096xK)
    gemm_bt<0><<<dim3(32, 32), 256, 0, stream>>>(
        y_bf, pi_t, row_norms, nullptr, w_bf, 4096, 4096, 4096);
    // 5) out = x @ W^T + bias : A=x_bf (8192xK), B=w_bf (4096xK)
    gemm_bt<1><<<dim3(32, 64), 256, 0, stream>>>(
        x_bf, w_bf, bias, out, nullptr, 8192, 4096, 4096);
}

// Round 2
// 825.764 us; speedup vs baseline: 1.0583x; 1.0583x over previous
//
#include <hip/hip_runtime.h>
#include <hip/hip_bf16.h>

typedef unsigned short u16;
typedef __bf16 bf16x8 __attribute__((ext_vector_type(8)));
typedef float f32x16 __attribute__((ext_vector_type(16)));

// ---------- helpers ----------

__device__ __forceinline__ u16 f32_to_bf16(float f) {
    unsigned int u = __float_as_uint(f);
    unsigned int r = (u + 0x7FFFu + ((u >> 16) & 1u)) >> 16;  // RNE
    return (u16)r;
}

__device__ __forceinline__ unsigned pack2(float a, float b) {
    return (unsigned)f32_to_bf16(a) | ((unsigned)f32_to_bf16(b) << 16);
}

__device__ __forceinline__ void load_lds16(const void* g, void* s) {
    __builtin_amdgcn_global_load_lds(
        (__attribute__((address_space(1))) void*)g,
        (__attribute__((address_space(3))) void*)s,
        16, 0, 0);
}

// ---------- kernel 1: x fp32 -> bf16 (8 elems/thread, 16B stores) ----------

__global__ __launch_bounds__(256) void convert_f32_bf16(
        const float* __restrict__ in, u16* __restrict__ out) {
    int i = blockIdx.x * 256 + threadIdx.x;            // grid exactly n/8
    const float4* in4 = (const float4*)in;
    float4 v0 = in4[(size_t)i * 2];
    float4 v1 = in4[(size_t)i * 2 + 1];
    uint4 r;
    r.x = pack2(v0.x, v0.y);
    r.y = pack2(v0.z, v0.w);
    r.z = pack2(v1.x, v1.y);
    r.w = pack2(v1.z, v1.w);
    ((uint4*)out)[i] = r;
}

// ---------- kernel 2: dequant indices -> y_bf (8 elems/thread) ----------

__global__ __launch_bounds__(256) void dequant_kernel(
        const int* __restrict__ idx, const float* __restrict__ cent,
        u16* __restrict__ out) {
    __shared__ float lut[16];
    if (threadIdx.x < 16) lut[threadIdx.x] = cent[threadIdx.x];
    __syncthreads();
    int i = blockIdx.x * 256 + threadIdx.x;
    const int4* in4 = (const int4*)idx;
    int4 a = in4[(size_t)i * 2];
    int4 b = in4[(size_t)i * 2 + 1];
    uint4 r;
    r.x = pack2(lut[a.x], lut[a.y]);
    r.y = pack2(lut[a.z], lut[a.w]);
    r.z = pack2(lut[b.x], lut[b.y]);
    r.w = pack2(lut[b.z], lut[b.w]);
    ((uint4*)out)[i] = r;
}

// ---------- kernel 3: Pi (4096x4096 fp32) -> Pi^T bf16 ----------

__global__ __launch_bounds__(256) void transpose_to_bf16(
        const float* __restrict__ Pi, u16* __restrict__ PiT) {
    __shared__ float tile[32][33];
    const int tx = threadIdx.x;      // 0..31
    const int ty = threadIdx.y;      // 0..7
    const int j0 = blockIdx.x * 32;  // Pi column block
    const int k0 = blockIdx.y * 32;  // Pi row block
#pragma unroll
    for (int i = 0; i < 4; i++)
        tile[ty + 8 * i][tx] = Pi[(size_t)(k0 + ty + 8 * i) * 4096 + j0 + tx];
    __syncthreads();
#pragma unroll
    for (int i = 0; i < 4; i++)
        PiT[(size_t)(j0 + ty + 8 * i) * 4096 + k0 + tx] =
            f32_to_bf16(tile[tx][ty + 8 * i]);
}

// ---------- GEMM: C[m][n] = sum_k A[m][k] * B[n][k]  (B stored N x K) ----------
// 128x128 block tile, BK=32, 4 waves, each wave = 64x64 via 2x2 grid of
// 32x32x16 bf16 MFMAs (2 k-steps per K-iter).
//
// LDS XOR swizzle: 16B chunk c of row r lives at chunk c ^ ((r>>1)&3).
//  - staging: global_load_lds dest stays lane-contiguous (tid*16B); each lane
//    fetches the permuted *global* chunk instead -> layout invariant holds.
//  - reads: per-lane swizzled offsets precomputed outside the K-loop
//    (loop-invariant), each 16-lane phase spreads across all 8 bank groups.
//
// MODE 0: store bf16, scale by aux[row]   (W = (yhat@Pi) * row_norms)
// MODE 1: store fp32, add aux[col]        (out = x@W^T + bias)

template <int MODE>
__global__ __launch_bounds__(256) void gemm_bt(
        const u16* __restrict__ A, const u16* __restrict__ Bm,
        const float* __restrict__ aux, float* __restrict__ Cf,
        u16* __restrict__ Cb, int M, int N, int K) {
    __shared__ u16 As[128 * 32];
    __shared__ u16 Bs[128 * 32];

    const int tid  = threadIdx.x;
    const int lane = tid & 63;
    const int wv   = tid >> 6;
    const int wr   = (wv >> 1) << 6;   // wave row offset in block tile
    const int wc   = (wv & 1) << 6;    // wave col offset in block tile
    const int m0   = blockIdx.y * 128;
    const int n0   = blockIdx.x * 128;

    // ---- staging addresses (swizzled global source, contiguous LDS dest)
    const int rT  = tid >> 2;                                  // row 0..63 (+64)
    const int cSw = (((tid & 3) ^ ((rT >> 1) & 3)) << 3);      // swizzled elem col
    const u16* Ag = A + (size_t)(m0 + rT) * K + cSw;
    const u16* Bg = Bm + (size_t)(n0 + rT) * K + cSw;
    u16* Asd = &As[tid * 8];   // = row rT, chunk (tid&3)  -> lane-contiguous
    u16* Bsd = &Bs[tid * 8];
    // note: row rT+64 has the same (r>>1)&3, so cSw is valid for both halves

    // ---- fragment read offsets (loop-invariant, swizzled)
    const int mrow = lane & 31;        // m/n within 32-tile
    const int kc   = lane >> 5;        // k chunk within k-step: 0 or 1
    int offA[2][2], offB[2][2];
#pragma unroll
    for (int mi = 0; mi < 2; mi++) {
        const int r  = wr + mi * 32 + mrow;
        const int sw = (r >> 1) & 3;
#pragma unroll
        for (int s = 0; s < 2; s++)
            offA[mi][s] = r * 32 + (((s * 2 + kc) ^ sw) << 3);
    }
#pragma unroll
    for (int ni = 0; ni < 2; ni++) {
        const int r  = wc + ni * 32 + mrow;
        const int sw = (r >> 1) & 3;
#pragma unroll
        for (int s = 0; s < 2; s++)
            offB[ni][s] = r * 32 + (((s * 2 + kc) ^ sw) << 3);
    }

    f32x16 acc[2][2];
#pragma unroll
    for (int i = 0; i < 2; i++)
#pragma unroll
        for (int j = 0; j < 2; j++)
#pragma unroll
            for (int e = 0; e < 16; e++) acc[i][j][e] = 0.f;

    for (int k0 = 0; k0 < K; k0 += 32) {
        load_lds16(Ag + k0, Asd);
        load_lds16(Ag + (size_t)64 * K + k0, Asd + 64 * 32);
        load_lds16(Bg + k0, Bsd);
        load_lds16(Bg + (size_t)64 * K + k0, Bsd + 64 * 32);
        __syncthreads();

        bf16x8 af[2][2], bfv[2][2];
#pragma unroll
        for (int mi = 0; mi < 2; mi++)
#pragma unroll
            for (int s = 0; s < 2; s++)
                af[mi][s] = *(const bf16x8*)&As[offA[mi][s]];
#pragma unroll
        for (int ni = 0; ni < 2; ni++)
#pragma unroll
            for (int s = 0; s < 2; s++)
                bfv[ni][s] = *(const bf16x8*)&Bs[offB[ni][s]];
#pragma unroll
        for (int s = 0; s < 2; s++)
#pragma unroll
            for (int mi = 0; mi < 2; mi++)
#pragma unroll
                for (int ni = 0; ni < 2; ni++)
                    acc[mi][ni] = __builtin_amdgcn_mfma_f32_32x32x16_bf16(
                        af[mi][s], bfv[ni][s], acc[mi][ni], 0, 0, 0);
        __syncthreads();
    }

    // ---- epilogue — 32x32 C/D: col = lane&31, row = (reg&3)+8*(reg>>2)+4*(lane>>5)
    const int colf = lane & 31;
    const int r4   = (lane >> 5) << 2;
#pragma unroll
    for (int mi = 0; mi < 2; mi++) {
#pragma unroll
        for (int ni = 0; ni < 2; ni++) {
            const int col = n0 + wc + ni * 32 + colf;
            float bv = 0.f;
            if (MODE == 1) bv = aux[col];
#pragma unroll
            for (int reg = 0; reg < 16; reg++) {
                const int row = m0 + wr + mi * 32 + (reg & 3) + ((reg >> 2) << 3) + r4;
                if (MODE == 0)
                    Cb[(size_t)row * N + col] = f32_to_bf16(acc[mi][ni][reg] * aux[row]);
                else
                    Cf[(size_t)row * N + col] = acc[mi][ni][reg] + bv;
            }
        }
    }
}

// ---------- launch ----------

extern "C" void kernel_launch(void* const* d_in, const int* in_sizes, int n_in,
                              void* d_out, int out_size, void* d_ws, size_t ws_size,
                              hipStream_t stream) {
    const float* x         = (const float*)d_in[0];   // (4,2048,4096) fp32
    const int*   indices   = (const int*)d_in[1];     // (4096,4096) int32
    const float* centroids = (const float*)d_in[2];   // (16,) fp32
    const float* Pi        = (const float*)d_in[3];   // (4096,4096) fp32
    const float* row_norms = (const float*)d_in[4];   // (4096,) fp32
    const float* bias      = (const float*)d_in[5];   // (4096,) fp32
    float* out = (float*)d_out;                       // (4,2048,4096) fp32

    // workspace layout (bf16 as u16): total 160 MiB
    u16* x_bf = (u16*)d_ws;                 // 8192*4096
    u16* y_bf = x_bf + (size_t)33554432;    // 4096*4096
    u16* pi_t = y_bf + (size_t)16777216;    // 4096*4096 (Pi transposed)
    u16* w_bf = pi_t + (size_t)16777216;    // 4096*4096

    convert_f32_bf16<<<16384, 256, 0, stream>>>(x, x_bf);
    dequant_kernel<<<8192, 256, 0, stream>>>(indices, centroids, y_bf);
    transpose_to_bf16<<<dim3(128, 128), dim3(32, 8), 0, stream>>>(Pi, pi_t);
    // W = (yhat @ Pi) * row_norms : A=y_bf (4096xK), B=pi_t (4096xK)
    gemm_bt<0><<<dim3(32, 32), 256, 0, stream>>>(
        y_bf, pi_t, row_norms, nullptr, w_bf, 4096, 4096, 4096);
    // out = x @ W^T + bias : A=x_bf (8192xK), B=w_bf (4096xK)
    gemm_bt<1><<<dim3(32, 64), 256, 0, stream>>>(
        x_bf, w_bf, bias, out, nullptr, 8192, 4096, 4096);
}

// Round 3
// 764.062 us; speedup vs baseline: 1.1438x; 1.0808x over previous
//
#include <hip/hip_runtime.h>
#include <hip/hip_bf16.h>

typedef unsigned short u16;
typedef __bf16 bf16x8 __attribute__((ext_vector_type(8)));
typedef float f32x16 __attribute__((ext_vector_type(16)));

// ---------- helpers ----------

__device__ __forceinline__ u16 f32_to_bf16(float f) {
    unsigned int u = __float_as_uint(f);
    unsigned int r = (u + 0x7FFFu + ((u >> 16) & 1u)) >> 16;  // RNE
    return (u16)r;
}

__device__ __forceinline__ unsigned pack2(float a, float b) {
    return (unsigned)f32_to_bf16(a) | ((unsigned)f32_to_bf16(b) << 16);
}

__device__ __forceinline__ void load_lds16(const void* g, void* s) {
    __builtin_amdgcn_global_load_lds(
        (__attribute__((address_space(1))) void*)g,
        (__attribute__((address_space(3))) void*)s,
        16, 0, 0);
}

// ---------- kernel 1: x fp32 -> bf16 (8 elems/thread, 16B stores) ----------

__global__ __launch_bounds__(256) void convert_f32_bf16(
        const float* __restrict__ in, u16* __restrict__ out) {
    int i = blockIdx.x * 256 + threadIdx.x;            // grid exactly n/8
    const float4* in4 = (const float4*)in;
    float4 v0 = in4[(size_t)i * 2];
    float4 v1 = in4[(size_t)i * 2 + 1];
    uint4 r;
    r.x = pack2(v0.x, v0.y);
    r.y = pack2(v0.z, v0.w);
    r.z = pack2(v1.x, v1.y);
    r.w = pack2(v1.z, v1.w);
    ((uint4*)out)[i] = r;
}

// ---------- kernel 2: dequant indices -> y_bf (8 elems/thread) ----------

__global__ __launch_bounds__(256) void dequant_kernel(
        const int* __restrict__ idx, const float* __restrict__ cent,
        u16* __restrict__ out) {
    __shared__ float lut[16];
    if (threadIdx.x < 16) lut[threadIdx.x] = cent[threadIdx.x];
    __syncthreads();
    int i = blockIdx.x * 256 + threadIdx.x;
    const int4* in4 = (const int4*)idx;
    int4 a = in4[(size_t)i * 2];
    int4 b = in4[(size_t)i * 2 + 1];
    uint4 r;
    r.x = pack2(lut[a.x], lut[a.y]);
    r.y = pack2(lut[a.z], lut[a.w]);
    r.z = pack2(lut[b.x], lut[b.y]);
    r.w = pack2(lut[b.z], lut[b.w]);
    ((uint4*)out)[i] = r;
}

// ---------- kernel 3: Pi (4096x4096 fp32) -> Pi^T bf16 ----------

__global__ __launch_bounds__(256) void transpose_to_bf16(
        const float* __restrict__ Pi, u16* __restrict__ PiT) {
    __shared__ float tile[32][33];
    const int tx = threadIdx.x;      // 0..31
    const int ty = threadIdx.y;      // 0..7
    const int j0 = blockIdx.x * 32;  // Pi column block
    const int k0 = blockIdx.y * 32;  // Pi row block
#pragma unroll
    for (int i = 0; i < 4; i++)
        tile[ty + 8 * i][tx] = Pi[(size_t)(k0 + ty + 8 * i) * 4096 + j0 + tx];
    __syncthreads();
#pragma unroll
    for (int i = 0; i < 4; i++)
        PiT[(size_t)(j0 + ty + 8 * i) * 4096 + k0 + tx] =
            f32_to_bf16(tile[tx][ty + 8 * i]);
}

// ---------- GEMM: C[m][n] = sum_k A[m][k] * B[n][k]  (B stored N x K) ----------
// 128x128 block tile, BK=64 as TWO 128x32 half-tiles per barrier pair
// (halves the vmcnt(0)+s_barrier drain events vs BK=32; 32 KB LDS keeps
// occupancy at the VGPR-bound ~3 blocks/CU, unlike m132's 64 KB regression).
// 4 waves, each wave = 64x64 via 2x2 grid of 32x32x16 bf16 MFMAs.
//
// LDS XOR swizzle within each half-tile: 16B chunk c of row r at c^((r>>1)&3).
// Staging permutes the *global* source chunk; global_load_lds dest stays
// lane-contiguous. Read offsets precomputed (loop-invariant); half 1 adds a
// +8KB constant that folds into the ds_read offset immediate.
//
// MODE 0: store bf16, scale by aux[row]   (W = (yhat@Pi) * row_norms)
// MODE 1: store fp32, add aux[col]        (out = x@W^T + bias)

template <int MODE>
__global__ __launch_bounds__(256) void gemm_bt(
        const u16* __restrict__ A, const u16* __restrict__ Bm,
        const float* __restrict__ aux, float* __restrict__ Cf,
        u16* __restrict__ Cb, int M, int N, int K) {
    __shared__ u16 As[2 * 128 * 32];   // half0 | half1
    __shared__ u16 Bs[2 * 128 * 32];

    const int tid  = threadIdx.x;
    const int lane = tid & 63;
    const int wv   = tid >> 6;
    const int wr   = (wv >> 1) << 6;   // wave row offset in block tile
    const int wc   = (wv & 1) << 6;    // wave col offset in block tile
    const int m0   = blockIdx.y * 128;
    const int n0   = blockIdx.x * 128;

    // ---- staging addresses (swizzled global source, contiguous LDS dest)
    const int rT  = tid >> 2;                                  // row 0..63 (+64)
    const int cSw = (((tid & 3) ^ ((rT >> 1) & 3)) << 3);      // swizzled elem col
    const u16* Ag = A + (size_t)(m0 + rT) * K + cSw;
    const u16* Bg = Bm + (size_t)(n0 + rT) * K + cSw;
    u16* Asd = &As[tid * 8];   // row rT, chunk (tid&3) -> lane-contiguous
    u16* Bsd = &Bs[tid * 8];

    // ---- fragment read offsets (loop-invariant, swizzled; half 0)
    const int mrow = lane & 31;        // m/n within 32-tile
    const int kc   = lane >> 5;        // k chunk within k-step: 0 or 1
    int offA[2][2], offB[2][2];
#pragma unroll
    for (int mi = 0; mi < 2; mi++) {
        const int r  = wr + mi * 32 + mrow;
        const int sw = (r >> 1) & 3;
#pragma unroll
        for (int s = 0; s < 2; s++)
            offA[mi][s] = r * 32 + (((s * 2 + kc) ^ sw) << 3);
    }
#pragma unroll
    for (int ni = 0; ni < 2; ni++) {
        const int r  = wc + ni * 32 + mrow;
        const int sw = (r >> 1) & 3;
#pragma unroll
        for (int s = 0; s < 2; s++)
            offB[ni][s] = r * 32 + (((s * 2 + kc) ^ sw) << 3);
    }

    f32x16 acc[2][2];
#pragma unroll
    for (int i = 0; i < 2; i++)
#pragma unroll
        for (int j = 0; j < 2; j++)
#pragma unroll
            for (int e = 0; e < 16; e++) acc[i][j][e] = 0.f;

    for (int k0 = 0; k0 < K; k0 += 64) {
        // stage both 32-wide half-tiles before one barrier
        load_lds16(Ag + k0, Asd);
        load_lds16(Ag + (size_t)64 * K + k0, Asd + 64 * 32);
        load_lds16(Bg + k0, Bsd);
        load_lds16(Bg + (size_t)64 * K + k0, Bsd + 64 * 32);
        load_lds16(Ag + k0 + 32, Asd + 4096);
        load_lds16(Ag + (size_t)64 * K + k0 + 32, Asd + 4096 + 64 * 32);
        load_lds16(Bg + k0 + 32, Bsd + 4096);
        load_lds16(Bg + (size_t)64 * K + k0 + 32, Bsd + 4096 + 64 * 32);
        __syncthreads();

#pragma unroll
        for (int h = 0; h < 2; h++) {
            const int hb = h * 4096;   // +8KB for half 1 (folds into ds offset)
            bf16x8 af[2][2], bfv[2][2];
#pragma unroll
            for (int mi = 0; mi < 2; mi++)
#pragma unroll
                for (int s = 0; s < 2; s++)
                    af[mi][s] = *(const bf16x8*)&As[hb + offA[mi][s]];
#pragma unroll
            for (int ni = 0; ni < 2; ni++)
#pragma unroll
                for (int s = 0; s < 2; s++)
                    bfv[ni][s] = *(const bf16x8*)&Bs[hb + offB[ni][s]];
#pragma unroll
            for (int s = 0; s < 2; s++)
#pragma unroll
                for (int mi = 0; mi < 2; mi++)
#pragma unroll
                    for (int ni = 0; ni < 2; ni++)
                        acc[mi][ni] = __builtin_amdgcn_mfma_f32_32x32x16_bf16(
                            af[mi][s], bfv[ni][s], acc[mi][ni], 0, 0, 0);
        }
        __syncthreads();
    }

    // ---- epilogue — 32x32 C/D: col = lane&31, row = (reg&3)+8*(reg>>2)+4*(lane>>5)
    const int colf = lane & 31;
    const int r4   = (lane >> 5) << 2;
#pragma unroll
    for (int mi = 0; mi < 2; mi++) {
#pragma unroll
        for (int ni = 0; ni < 2; ni++) {
            const int col = n0 + wc + ni * 32 + colf;
            float bv = 0.f;
            if (MODE == 1) bv = aux[col];
#pragma unroll
            for (int reg = 0; reg < 16; reg++) {
                const int row = m0 + wr + mi * 32 + (reg & 3) + ((reg >> 2) << 3) + r4;
                if (MODE == 0)
                    Cb[(size_t)row * N + col] = f32_to_bf16(acc[mi][ni][reg] * aux[row]);
                else
                    Cf[(size_t)row * N + col] = acc[mi][ni][reg] + bv;
            }
        }
    }
}

// ---------- launch ----------

extern "C" void kernel_launch(void* const* d_in, const int* in_sizes, int n_in,
                              void* d_out, int out_size, void* d_ws, size_t ws_size,
                              hipStream_t stream) {
    const float* x         = (const float*)d_in[0];   // (4,2048,4096) fp32
    const int*   indices   = (const int*)d_in[1];     // (4096,4096) int32
    const float* centroids = (const float*)d_in[2];   // (16,) fp32
    const float* Pi        = (const float*)d_in[3];   // (4096,4096) fp32
    const float* row_norms = (const float*)d_in[4];   // (4096,) fp32
    const float* bias      = (const float*)d_in[5];   // (4096,) fp32
    float* out = (float*)d_out;                       // (4,2048,4096) fp32

    // workspace layout (bf16 as u16): total 160 MiB
    u16* x_bf = (u16*)d_ws;                 // 8192*4096
    u16* y_bf = x_bf + (size_t)33554432;    // 4096*4096
    u16* pi_t = y_bf + (size_t)16777216;    // 4096*4096 (Pi transposed)
    u16* w_bf = pi_t + (size_t)16777216;    // 4096*4096

    convert_f32_bf16<<<16384, 256, 0, stream>>>(x, x_bf);
    dequant_kernel<<<8192, 256, 0, stream>>>(indices, centroids, y_bf);
    transpose_to_bf16<<<dim3(128, 128), dim3(32, 8), 0, stream>>>(Pi, pi_t);
    // W = (yhat @ Pi) * row_norms : A=y_bf (4096xK), B=pi_t (4096xK)
    gemm_bt<0><<<dim3(32, 32), 256, 0, stream>>>(
        y_bf, pi_t, row_norms, nullptr, w_bf, 4096, 4096, 4096);
    // out = x @ W^T + bias : A=x_bf (8192xK), B=w_bf (4096xK)
    gemm_bt<1><<<dim3(32, 64), 256, 0, stream>>>(
        x_bf, w_bf, bias, out, nullptr, 8192, 4096, 4096);
}